// Round 6
// baseline (405.708 us; speedup 1.0000x reference)
//
#include <hip/hip_runtime.h>
#include <hip/hip_bf16.h>

#define D 256        // D_IN
#define DOUT 1024
#define STACKS 4
#define NTILES 64    // 1024 / 16

typedef __attribute__((ext_vector_type(8))) short bf16x8;
typedef __attribute__((ext_vector_type(4))) float f32x4;

// ---------------- FWHT-256: lane l holds elements 4l..4l+3 ----------------
__device__ __forceinline__ void fwht256(float v[4], int lane) {
    float a0 = v[0] + v[1];
    float a1 = v[0] - v[1];
    float a2 = v[2] + v[3];
    float a3 = v[2] - v[3];
    v[0] = a0 + a2; v[2] = a0 - a2;
    v[1] = a1 + a3; v[3] = a1 - a3;
#pragma unroll
    for (int d = 1; d < 64; d <<= 1) {
        const bool upper = (lane & d) != 0;
#pragma unroll
        for (int j = 0; j < 4; ++j) {
            float o = __shfl_xor(v[j], d, 64);
            v[j] = upper ? (o - v[j]) : (v[j] + o);
        }
    }
}

// ---------------- Kernel 1: build Bpack (W^T in MFMA fragment order) -------
// B[k][o] = W[o,k]. Fragment layout for mfma_f32_16x16x32_bf16 B-operand:
// lane l supplies B[kb*32 + (l>>4)*8 + j][nt*16 + (l&15)], j=0..7.
// Each (nt,kb) block = 32x16 = 512 bf16 = 64 lanes x 8.
// Bpack bf16 address:
//   ((o>>4)*8 + (k>>5))*512 + (((k>>3)&3)*16 + (o&15))*8 + (k&7)
__global__ __launch_bounds__(256) void build_bpack(
    const float* __restrict__ s1, const float* __restrict__ s2,
    const float* __restrict__ g_mu, const float* __restrict__ g_rho,
    const float* __restrict__ eps, __hip_bfloat16* __restrict__ bpack)
{
    const int wid  = blockIdx.x * 4 + (threadIdx.x >> 6);  // 0..1023
    const int lane = threadIdx.x & 63;
    const int k = wid & 255;      // W column (input-feature index)
    const int s = wid >> 8;       // stack

    const int e0 = lane * 4;
    float v[4];
#pragma unroll
    for (int j = 0; j < 4; ++j) {
        const int e = e0 + j;
        const float g = g_mu[s * D + e]
                      + log1pf(expf(g_rho[s * D + e])) * eps[s * D + e];
        v[j] = (__builtin_popcount(e & k) & 1) ? -g : g;   // g ⊙ H[:,k]
    }
    fwht256(v, lane);                                      // H · (g ⊙ H[:,k])
    const float s2k = s2[s * D + k];
#pragma unroll
    for (int j = 0; j < 4; ++j) {
        const int e = e0 + j;
        const int o = s * D + e;                           // output-feature idx
        const float w = s1[s * D + e] * v[j] * s2k;        // W[o,k]
        const int addr = ((o >> 4) * 8 + (k >> 5)) * 512
                       + (((k >> 3) & 3) * 16 + (o & 15)) * 8 + (k & 7);
        bpack[addr] = __float2bfloat16(w);
    }
}

// ---------------- Kernel 2: out = x @ W^T via MFMA -------------------------
__device__ __forceinline__ unsigned pk2(float a, float b) {
    union { __hip_bfloat162 h; unsigned u; } c;
    c.h = __float22bfloat162_rn(float2{a, b});
    return c.u;
}
__device__ __forceinline__ bf16x8 as_frag(const unsigned u[4]) {
    union { unsigned u[4]; bf16x8 v; } c;
    c.u[0] = u[0]; c.u[1] = u[1]; c.u[2] = u[2]; c.u[3] = u[3];
    return c.v;
}

__global__ __launch_bounds__(256) void whvi_gemm(
    const float* __restrict__ x, const bf16x8* __restrict__ bpack,
    float* __restrict__ out, int nrows)
{
    const int lane = threadIdx.x & 63;
    const int wid  = threadIdx.x >> 6;
    const int rbase = (blockIdx.x * 4 + wid) * 32;   // 32 rows per wave
    if (rbase >= nrows) return;
    const int rlo = lane & 15;       // A row within frag / C col within tile
    const int g4  = lane >> 4;       // lane group 0..3

    // A fragments: 2 row-frags x 8 k-blocks, 8 bf16 each.
    // a_frag[j] = A[rlo][kb*32 + g4*8 + j]
    unsigned a_pk[2][8][4];
#pragma unroll
    for (int rf = 0; rf < 2; ++rf) {
        const float* xr = x + (size_t)(rbase + rf * 16 + rlo) * D + g4 * 8;
#pragma unroll
        for (int kb = 0; kb < 8; ++kb) {
            const float4 f0 = *reinterpret_cast<const float4*>(xr + kb * 32);
            const float4 f1 = *reinterpret_cast<const float4*>(xr + kb * 32 + 4);
            a_pk[rf][kb][0] = pk2(f0.x, f0.y);
            a_pk[rf][kb][1] = pk2(f0.z, f0.w);
            a_pk[rf][kb][2] = pk2(f1.x, f1.y);
            a_pk[rf][kb][3] = pk2(f1.z, f1.w);
        }
    }

    const bf16x8* bp = bpack + lane;
    for (int nt = 0; nt < NTILES; ++nt) {
        f32x4 acc0 = {0.f, 0.f, 0.f, 0.f};
        f32x4 acc1 = {0.f, 0.f, 0.f, 0.f};
#pragma unroll
        for (int kb = 0; kb < 8; ++kb) {
            const bf16x8 b = bp[(nt * 8 + kb) * 64];
            acc0 = __builtin_amdgcn_mfma_f32_16x16x32_bf16(
                       as_frag(a_pk[0][kb]), b, acc0, 0, 0, 0);
            acc1 = __builtin_amdgcn_mfma_f32_16x16x32_bf16(
                       as_frag(a_pk[1][kb]), b, acc1, 0, 0, 0);
        }
        // C/D layout (m89-verified): lane holds C[g4*4 + q][rlo] per 16x16 tile.
        float* o = out + (size_t)rbase * DOUT + nt * 16 + rlo;
#pragma unroll
        for (int q = 0; q < 4; ++q) {
            o[(size_t)(g4 * 4 + q) * DOUT]      = acc0[q];
            o[(size_t)(16 + g4 * 4 + q) * DOUT] = acc1[q];
        }
    }
}

extern "C" void kernel_launch(void* const* d_in, const int* in_sizes, int n_in,
                              void* d_out, int out_size, void* d_ws, size_t ws_size,
                              hipStream_t stream) {
    const float* x     = (const float*)d_in[0];
    const float* s1    = (const float*)d_in[1];
    const float* s2    = (const float*)d_in[2];
    const float* g_mu  = (const float*)d_in[3];
    const float* g_rho = (const float*)d_in[4];
    const float* eps   = (const float*)d_in[5];
    float* out = (float*)d_out;

    __hip_bfloat16* bpack = (__hip_bfloat16*)d_ws;   // 512 KB

    // 1024 waves: one per (stack, W-column) pair.
    build_bpack<<<256, 256, 0, stream>>>(s1, s2, g_mu, g_rho, eps, bpack);

    const int nrows = in_sizes[0] / D;               // 65536
    const int grid  = nrows / 128;                   // 4 waves x 32 rows per block
    whvi_gemm<<<grid, 256, 0, stream>>>(x, (const bf16x8*)bpack, out, nrows);
}